// Round 1
// baseline (44.842 us; speedup 1.0000x reference)
//
#include <hip/hip_runtime.h>

// Depthwise 4x4 FIR blur, pad=(2,1) both H and W, fp32.
// x: [32, 256, 64, 64], kernel: [4,4], out: [32, 256, 64, 64].
// One block per (n,c) plane; plane staged in padded LDS; each thread
// computes a 4x4 output block from a 7x7 register window.

#define SM_STRIDE 68   // 67 cols padded to 68 floats
#define SM_ROWS   67   // 64 + pad_before(2) + pad_after(1)

__global__ __launch_bounds__(256) void Blur_910533066888_kernel(
    const float* __restrict__ x,
    const float* __restrict__ k,
    float* __restrict__ out)
{
    __shared__ float sm[SM_ROWS * SM_STRIDE];

    const int t = threadIdx.x;
    const int plane = blockIdx.x;                 // n*C + c
    const float* __restrict__ xin = x + (size_t)plane * 4096;
    float* __restrict__ op = out + (size_t)plane * 4096;

    // --- zero the padded tile (borders must be 0) ---
    #pragma unroll
    for (int i = 0; i < 18; ++i) {
        int idx = t + i * 256;
        if (idx < SM_ROWS * SM_STRIDE) sm[idx] = 0.0f;
    }
    __syncthreads();

    // --- coalesced float4 load of the 64x64 plane into padded position ---
    #pragma unroll
    for (int it = 0; it < 4; ++it) {
        int f4  = t + it * 256;        // float4 index in [0,1024)
        int row = f4 >> 4;             // f4*4 / 64
        int col = (f4 & 15) << 2;      // (f4*4) % 64
        float4 v = reinterpret_cast<const float4*>(xin)[f4];
        float* dst = &sm[(row + 2) * SM_STRIDE + (col + 2)];
        dst[0] = v.x; dst[1] = v.y; dst[2] = v.z; dst[3] = v.w;
    }

    // --- flipped taps (true convolution): kf[i][j] = k[3-i][3-j] ---
    float kf[4][4];
    #pragma unroll
    for (int i = 0; i < 4; ++i)
        #pragma unroll
        for (int j = 0; j < 4; ++j)
            kf[i][j] = k[(3 - i) * 4 + (3 - j)];

    __syncthreads();

    // --- each thread: 4x4 output block ---
    const int ty = (t >> 4) << 2;      // output row base (0..60)
    const int tx = (t & 15) << 2;      // output col base (0..60)

    float win[7][7];
    #pragma unroll
    for (int r = 0; r < 7; ++r)
        #pragma unroll
        for (int c = 0; c < 7; ++c)
            win[r][c] = sm[(ty + r) * SM_STRIDE + (tx + c)];

    #pragma unroll
    for (int r = 0; r < 4; ++r) {
        float a0 = 0.f, a1 = 0.f, a2 = 0.f, a3 = 0.f;
        #pragma unroll
        for (int i = 0; i < 4; ++i) {
            #pragma unroll
            for (int j = 0; j < 4; ++j) {
                const float w = kf[i][j];
                a0 = fmaf(w, win[r + i][0 + j], a0);
                a1 = fmaf(w, win[r + i][1 + j], a1);
                a2 = fmaf(w, win[r + i][2 + j], a2);
                a3 = fmaf(w, win[r + i][3 + j], a3);
            }
        }
        float4 acc = make_float4(a0, a1, a2, a3);
        *reinterpret_cast<float4*>(&op[(ty + r) * 64 + tx]) = acc;
    }
}

extern "C" void kernel_launch(void* const* d_in, const int* in_sizes, int n_in,
                              void* d_out, int out_size, void* d_ws, size_t ws_size,
                              hipStream_t stream)
{
    const float* x = (const float*)d_in[0];
    const float* k = (const float*)d_in[1];
    float* out = (float*)d_out;

    const int planes = 32 * 256;   // N*C
    Blur_910533066888_kernel<<<planes, 256, 0, stream>>>(x, k, out);
}